// Round 7
// baseline (1958.721 us; speedup 1.0000x reference)
//
#include <hip/hip_runtime.h>

typedef _Float16 f16;
typedef _Float16 h2 __attribute__((ext_vector_type(2)));
typedef unsigned int u32;

#define TB  256
#define TTT 2000
#define INW 42
#define HV  24
#define HN  48
#define HD  96
#define NTH 640

// act ring (depth 8), f16 regions per slot (all 16B-aligned):
// DIN [0,128):   vadh[0,24) | noih[24,72) | x[72,114) | pad       == den_wih col order
// DH  [128,224): denh
// NIN [224,320): tmp[224,248) | vadh[248,272) | x[272,314) | pad  == noise_wih col order
// NH  [320,384): noih[320,368) | pad
// Skews (tick k): vad t=k-1 | noise t=k-3 (B: inputs t=k-2) | den t=k-5 (B: inputs t=k-4) | out t=k-6
// h(t) lives in slot t&7 for every region.
#define DIN 0
#define DH  128
#define NIN 224
#define NH  320
#define ACTW 384

__device__ __forceinline__ float fsigm(float v) {
    return __builtin_amdgcn_rcpf(1.0f + __builtin_amdgcn_exp2f(-1.44269504089f * v));
}
__device__ __forceinline__ float ftanh(float v) {
    float e = __builtin_amdgcn_exp2f(2.88539008178f * v);
    return 1.0f - 2.0f * __builtin_amdgcn_rcpf(e + 1.0f);
}
__device__ __forceinline__ float dot2f(u32 a, u32 w, float c) {
#if __has_builtin(__builtin_amdgcn_fdot2)
    return __builtin_amdgcn_fdot2(__builtin_bit_cast(h2, a), __builtin_bit_cast(h2, w), c, false);
#else
    h2 av = __builtin_bit_cast(h2, a), wv = __builtin_bit_cast(h2, w);
    return c + (float)av[0] * (float)wv[0] + (float)av[1] * (float)wv[1];
#endif
}
__device__ __forceinline__ u32 packw(float a, float b) {
    h2 v; v[0] = (f16)a; v[1] = (f16)b;
    return __builtin_bit_cast(u32, v);
}
// DPP adds: xor quad_perm (0xB1,0x4E) direction-free; row_ror 0x124/0x128 only for
// full-row rotate-accumulate (every lane ends with the total, direction irrelevant).
template<int CTRL>
__device__ __forceinline__ float dpp_add(float x) {
    int y = __builtin_amdgcn_mov_dpp(__builtin_bit_cast(int, x), CTRL, 0xF, 0xF, true);
    return x + __builtin_bit_cast(float, y);
}

// raw barrier: flush LDS ops, do NOT drain vmcnt (x prefetch + global stores stay in flight)
#define SYNCB() asm volatile("s_waitcnt lgkmcnt(0)\n\ts_barrier" ::: "memory")

#define ACCI(AV, W, IDX) do { u32 _a = (AV); \
    rr = dot2f(_a, W[0][IDX], rr); zz = dot2f(_a, W[1][IDX], zz); an = dot2f(_a, W[2][IDX], an); } while (0)
#define ACCH(AV, W, IDX) do { u32 _a = (AV); \
    rr = dot2f(_a, W[0][IDX], rr); zz = dot2f(_a, W[1][IDX], zz); hn = dot2f(_a, W[2][IDX], hn); } while (0)
#define ACCI4(U4, W, M0) do { uint4 _u4 = (U4); \
    ACCI(_u4.x, W, (M0)+0); ACCI(_u4.y, W, (M0)+1); ACCI(_u4.z, W, (M0)+2); ACCI(_u4.w, W, (M0)+3); } while (0)
#define ACCH4(U4, W, M0) do { uint4 _u4 = (U4); \
    ACCH(_u4.x, W, (M0)+0); ACCH(_u4.y, W, (M0)+1); ACCH(_u4.z, W, (M0)+2); ACCH(_u4.w, W, (M0)+3); } while (0)
#define RED4_Q() do { \
    rr = dpp_add<0xB1>(rr); rr = dpp_add<0x4E>(rr); \
    zz = dpp_add<0xB1>(zz); zz = dpp_add<0x4E>(zz); \
    an = dpp_add<0xB1>(an); an = dpp_add<0x4E>(an); \
    hn = dpp_add<0xB1>(hn); hn = dpp_add<0x4E>(hn); } while (0)
#define RED4_1() do { \
    rr = dpp_add<0xB1>(rr); zz = dpp_add<0xB1>(zz); \
    an = dpp_add<0xB1>(an); hn = dpp_add<0xB1>(hn); } while (0)

template<int N> struct IC { static constexpr int val = N; };

__global__ __launch_bounds__(NTH, 1) void rnnoise_kernel(
    const float* __restrict__ gx,
    const float* __restrict__ in_w,      const float* __restrict__ in_b,
    const float* __restrict__ vad_wih,   const float* __restrict__ vad_whh,
    const float* __restrict__ vad_bih,   const float* __restrict__ vad_bhh,
    const float* __restrict__ vad_out_w, const float* __restrict__ vad_out_b,
    const float* __restrict__ noise_wih, const float* __restrict__ noise_whh,
    const float* __restrict__ noise_bih, const float* __restrict__ noise_bhh,
    const float* __restrict__ den_wih,   const float* __restrict__ den_whh,
    const float* __restrict__ den_bih,   const float* __restrict__ den_bhh,
    const float* __restrict__ out_w,     const float* __restrict__ out_b,
    float* __restrict__ gains, float* __restrict__ vout)
{
    __shared__ __align__(16) f16 act[8][ACTW];   // 6 KB

    const int tid = threadIdx.x, wid = tid >> 6, lane = tid & 63;
    const int b = blockIdx.x;

    // zero all slots (initial states AND pads)
    #pragma unroll
    for (int i = 0; i < 3; ++i) {
        int idx = tid + i * NTH;
        if (idx < 8 * ACTW / 2) ((u32*)act)[idx] = 0u;
    }
    __syncthreads();

    const int role = (wid == 9) ? 2 : ((wid == 4 || wid == 5 || wid == 8) ? 1 : 0);

    if (role == 0) {
        // ========== DEN: A computes t=k-5 (hh + carried inputs), B prefetches inputs t=k-4 ==========
        const int dwi = (wid < 4) ? wid : (wid - 2);       // 0..5
        const int u = 16 * dwi + (lane >> 2), q = lane & 3;
        u32 wdi[3][16], wdh[3][12];
        #pragma unroll
        for (int g = 0; g < 3; ++g) {
            const float* wi = den_wih + (g * HD + u) * 114;   // cols [vad|noi|x] == DIN order
            #pragma unroll
            for (int m = 0; m < 16; ++m) {
                int c = 32 * q + 2 * m;
                float a  = (c     < 114) ? wi[c]     : 0.f;
                float b2 = (c + 1 < 114) ? wi[c + 1] : 0.f;
                wdi[g][m] = packw(a, b2);
            }
            const float* wh = den_whh + (g * HD + u) * HD + 24 * q;
            #pragma unroll
            for (int m = 0; m < 12; ++m) wdh[g][m] = packw(wh[2*m], wh[2*m+1]);
        }
        const float bdr  = den_bih[u]        + den_bhh[u];
        const float bdz  = den_bih[HD + u]   + den_bhh[HD + u];
        const float bdni = den_bih[2*HD + u];
        const float bdnh = den_bhh[2*HD + u];
        float hreg = 0.f;
        float rr = 0.f, zz = 0.f, an = 0.f;   // carried input-side partials (per-lane)

        auto step = [&](auto PC, int k) {
            constexpr int P   = decltype(PC)::val;
            constexpr int SHH = (P + 2) & 7;   // denh(k-6)
            constexpr int SWR = (P + 3) & 7;   // write denh(k-5)
            constexpr int SB  = (P + 4) & 7;   // inputs of t=k-4
            // issue B reads early (latency hide under A)
            uint4 a0{}, a1{}, a2{}, a3{};
            if (k >= 4 && k < TTT + 4) {
                const uint4* ip = (const uint4*)&act[SB][DIN + 32 * q];
                a0 = ip[0]; a1 = ip[1]; a2 = ip[2]; a3 = ip[3];
            }
            if (k >= 5 && k < TTT + 5) {   // phase A: t = k-5
                const uint4* hp = (const uint4*)&act[SHH][DH + 24 * q];
                uint4 h0 = hp[0], h1 = hp[1], h2 = hp[2];
                float hn = 0.f;
                ACCH4(h0, wdh, 0); ACCH4(h1, wdh, 4); ACCH4(h2, wdh, 8);
                RED4_Q();
                if (q == 0) {
                    float r = fsigm(rr + bdr);
                    float z = fsigm(zz + bdz);
                    float n = ftanh(an + bdni + r * (hn + bdnh));
                    hreg = z * (hreg - n) + n;
                    act[SWR][DH + u] = (f16)hreg;
                }
                rr = 0.f; zz = 0.f; an = 0.f;
            }
            if (k >= 4 && k < TTT + 4) {   // phase B: input partials for t = k-4
                ACCI4(a0, wdi, 0); ACCI4(a1, wdi, 4); ACCI4(a2, wdi, 8); ACCI4(a3, wdi, 12);
            }
            SYNCB();
        };
        #pragma clang loop unroll(disable)
        for (int k0 = 0; k0 < TTT + 8; k0 += 8) {
            step(IC<0>{},k0);   step(IC<1>{},k0+1); step(IC<2>{},k0+2); step(IC<3>{},k0+3);
            step(IC<4>{},k0+4); step(IC<5>{},k0+5); step(IC<6>{},k0+6); step(IC<7>{},k0+7);
        }

    } else if (role == 1) {
        // ========== NOISE: A computes t=k-3, B prefetches inputs t=k-2; OUT t=k-6 ==========
        const int nwi = (wid == 4) ? 0 : ((wid == 5) ? 1 : 2);
        const int u = 16 * nwi + (lane >> 2), q = lane & 3;
        const int o = 8 * nwi + (lane >> 3), s8 = lane & 7;
        const int oc = (o < 22) ? o : 0;
        u32 wni[3][12], wnh[3][8], wo[6];
        #pragma unroll
        for (int g = 0; g < 3; ++g) {
            const float* wi = noise_wih + (g * HN + u) * 90;   // cols [tmp|vad|x] == NIN order
            #pragma unroll
            for (int m = 0; m < 12; ++m) {
                int c = 24 * q + 2 * m;
                float a  = (c     < 90) ? wi[c]     : 0.f;
                float b2 = (c + 1 < 90) ? wi[c + 1] : 0.f;
                wni[g][m] = packw(a, b2);
            }
            const float* wh = noise_whh + (g * HN + u) * HN;
            #pragma unroll
            for (int m = 0; m < 8; ++m) {
                int c = 16 * q + 2 * m;                        // NH dim (pad -> 0 weight)
                float a  = (c     < 48) ? wh[c]     : 0.f;
                float b2 = (c + 1 < 48) ? wh[c + 1] : 0.f;
                wnh[g][m] = packw(a, b2);
            }
        }
        #pragma unroll
        for (int m = 0; m < 6; ++m)
            wo[m] = packw(out_w[oc*HD + 12*s8 + 2*m], out_w[oc*HD + 12*s8 + 2*m + 1]);
        const float bnr  = noise_bih[u]        + noise_bhh[u];
        const float bnz  = noise_bih[HN + u]   + noise_bhh[HN + u];
        const float bnni = noise_bih[2*HN + u];
        const float bnnh = noise_bhh[2*HN + u];
        const float bo   = out_b[oc];
        float hreg = 0.f;
        float rr = 0.f, zz = 0.f, an = 0.f;   // carried input-side partials

        auto step = [&](auto PC, int k) {
            constexpr int P   = decltype(PC)::val;
            constexpr int SHH = (P + 4) & 7;   // noih(k-4)
            constexpr int SWR = (P + 5) & 7;   // write noih(k-3)
            constexpr int SB  = (P + 6) & 7;   // NIN inputs of t=k-2
            constexpr int SOT = (P + 2) & 7;   // denh(k-6) for OUT
            uint4 a0{}, a1{}, a2{};
            if (k >= 2 && k < TTT + 2) {
                const uint4* ip = (const uint4*)&act[SB][NIN + 24 * q];
                a0 = ip[0]; a1 = ip[1]; a2 = ip[2];
            }
            uint2 d0{}, d1{}, d2{};
            if (k >= 6 && k < TTT + 6) {
                const uint2* dp = (const uint2*)&act[SOT][DH + 12 * s8];
                d0 = dp[0]; d1 = dp[1]; d2 = dp[2];
            }
            if (k >= 3 && k < TTT + 3) {   // phase A: t = k-3
                const uint4* hp = (const uint4*)&act[SHH][NH + 16 * q];
                uint4 h0 = hp[0], h1 = hp[1];
                float hn = 0.f;
                ACCH4(h0, wnh, 0); ACCH4(h1, wnh, 4);
                RED4_Q();
                if (q == 0) {
                    float r = fsigm(rr + bnr);
                    float z = fsigm(zz + bnz);
                    float n = ftanh(an + bnni + r * (hn + bnnh));
                    hreg = z * (hreg - n) + n;
                    f16 hh = (f16)hreg;
                    act[SWR][NH + u]       = hh;   // noise hh source
                    act[SWR][DIN + 24 + u] = hh;   // den input copy
                }
                rr = 0.f; zz = 0.f; an = 0.f;
            }
            if (k >= 6 && k < TTT + 6) {   // OUT: gains(t=k-6) over denh(k-6)
                float acc = 0;
                acc = dot2f(d0.x, wo[0], acc); acc = dot2f(d0.y, wo[1], acc);
                acc = dot2f(d1.x, wo[2], acc); acc = dot2f(d1.y, wo[3], acc);
                acc = dot2f(d2.x, wo[4], acc); acc = dot2f(d2.y, wo[5], acc);
                acc = dpp_add<0xB1>(acc); acc = dpp_add<0x4E>(acc);
                acc += __shfl_xor(acc, 4);
                if (s8 == 0 && o < 22)
                    gains[((size_t)b * TTT + (k - 6)) * 22 + o] = fsigm(acc + bo);
            }
            if (k >= 2 && k < TTT + 2) {   // phase B: input partials for t = k-2
                ACCI4(a0, wni, 0); ACCI4(a1, wni, 4); ACCI4(a2, wni, 8);
            }
            SYNCB();
        };
        #pragma clang loop unroll(disable)
        for (int k0 = 0; k0 < TTT + 8; k0 += 8) {
            step(IC<0>{},k0);   step(IC<1>{},k0+1); step(IC<2>{},k0+2); step(IC<3>{},k0+3);
            step(IC<4>{},k0+4); step(IC<5>{},k0+5); step(IC<6>{},k0+6); step(IC<7>{},k0+7);
        }

    } else {
        // ========== VAD wave: x stage + tmp(k) + vad GRU(t=k-1) + vad_out(t=k-1) ==========
        const int l = lane;
        const int u = (l < 48) ? (l >> 1) : 0, q2 = l & 1;
        u32 wvi[3][6], wvh[3][6], wtm[12];
        float bvr = 0, bvz = 0, bvni = 0, bvnh = 0, btm = 0, wvo_u = 0;
        if (l < 48) {
            #pragma unroll
            for (int g = 0; g < 3; ++g) {
                const float* wi = vad_wih + (g * HV + u) * HV + 12 * q2;
                const float* wh = vad_whh + (g * HV + u) * HV + 12 * q2;
                #pragma unroll
                for (int j = 0; j < 6; ++j) {
                    wvi[g][j] = packw(wi[2*j], wi[2*j+1]);
                    wvh[g][j] = packw(wh[2*j], wh[2*j+1]);
                }
            }
            #pragma unroll
            for (int j = 0; j < 12; ++j) {
                int c0 = 24 * q2 + 2 * j;
                float a = (c0     < INW) ? in_w[u * INW + c0]     : 0.f;
                float c = (c0 + 1 < INW) ? in_w[u * INW + c0 + 1] : 0.f;
                wtm[j] = packw(a, c);
            }
            bvr  = vad_bih[u]        + vad_bhh[u];
            bvz  = vad_bih[HV + u]   + vad_bhh[HV + u];
            bvni = vad_bih[2*HV + u];
            bvnh = vad_bhh[2*HV + u];
            btm  = in_b[u];
            if (q2 == 0) wvo_u = vad_out_w[u];
        }
        const float bvo = vad_out_b[0];
        float hreg = 0.f;

        float xa = 0, xb = 0, xc = 0, xd = 0;   // 4-deep x prefetch (reg chosen by P&3)
        if (l < INW) {
            xa = gx[((size_t)b * TTT + 0) * INW + l];
            xb = gx[((size_t)b * TTT + 1) * INW + l];
            xc = gx[((size_t)b * TTT + 2) * INW + l];
            xd = gx[((size_t)b * TTT + 3) * INW + l];
        }

        auto step = [&](auto PC, int k) {
            constexpr int P  = decltype(PC)::val;
            constexpr int ST = (P + 7) & 7;   // slot of t=k-1 (tmp read, vadh write)
            constexpr int SH = (P + 6) & 7;   // vadh(k-2)
            if (k < TTT && l < INW) {         // stage x(k) into both regions of slot P
                float xv;
                if constexpr ((P & 3) == 0) xv = xa; else if constexpr ((P & 3) == 1) xv = xb;
                else if constexpr ((P & 3) == 2) xv = xc; else xv = xd;
                f16 xh = (f16)xv;
                act[P][NIN + 48 + l] = xh;
                act[P][DIN + 72 + l] = xh;
            }
            if (k + 4 < TTT && l < INW) {     // refill phase register with x(k+4)
                float xv = gx[((size_t)b * TTT + (k + 4)) * INW + l];
                if constexpr ((P & 3) == 0) xa = xv; else if constexpr ((P & 3) == 1) xb = xv;
                else if constexpr ((P & 3) == 2) xc = xv; else xd = xv;
            }
            if (k >= 1 && k <= TTT) {         // vad GRU t = k-1
                float rr = 0, zz = 0, an = 0, hn = 0;
                if (l < 48) {
                    const uint2* tp = (const uint2*)&act[ST][NIN + 12 * q2];       // tmp(t)
                    const uint2* hp = (const uint2*)&act[SH][NIN + 24 + 12 * q2];  // vadh(t-1)
                    #pragma unroll
                    for (int v = 0; v < 3; ++v) {
                        uint2 a = tp[v]; ACCI(a.x, wvi, 2*v); ACCI(a.y, wvi, 2*v+1);
                        uint2 h = hp[v]; ACCH(h.x, wvh, 2*v); ACCH(h.y, wvh, 2*v+1);
                    }
                    RED4_1();
                    if (q2 == 0) {
                        float r = fsigm(rr + bvr);
                        float z = fsigm(zz + bvz);
                        float n = ftanh(an + bvni + r * (hn + bvnh));
                        hreg = z * (hreg - n) + n;
                        f16 hh = (f16)hreg;
                        act[ST][NIN + 24 + u] = hh;   // noise/vad hh source
                        act[ST][DIN + u]      = hh;   // den input copy
                    }
                }
                float val = (l < 48 && q2 == 0) ? (wvo_u * hreg) : 0.f;
                val = dpp_add<0xB1>(val);  val = dpp_add<0x4E>(val);
                val = dpp_add<0x124>(val); val = dpp_add<0x128>(val);   // full 16-row sum
                val += __shfl_xor(val, 16); val += __shfl_xor(val, 32);
                if (l == 0) vout[(size_t)b * TTT + (k - 1)] = fsigm(val + bvo);
            }
            if (k < TTT && l < 48) {          // tmp(k) from x(k) staged this tick (intra-wave)
                float acc = 0;
                const uint4* xp = (const uint4*)&act[P][NIN + 48 + 24 * q2];
                uint4 a = xp[0], b2 = xp[1], c2 = xp[2];
                acc = dot2f(a.x,  wtm[0], acc);  acc = dot2f(a.y,  wtm[1], acc);
                acc = dot2f(a.z,  wtm[2], acc);  acc = dot2f(a.w,  wtm[3], acc);
                acc = dot2f(b2.x, wtm[4], acc);  acc = dot2f(b2.y, wtm[5], acc);
                acc = dot2f(b2.z, wtm[6], acc);  acc = dot2f(b2.w, wtm[7], acc);
                acc = dot2f(c2.x, wtm[8], acc);  acc = dot2f(c2.y, wtm[9], acc);
                acc = dot2f(c2.z, wtm[10], acc); acc = dot2f(c2.w, wtm[11], acc);
                acc = dpp_add<0xB1>(acc);
                if (q2 == 0) act[P][NIN + u] = (f16)ftanh(acc + btm);
            }
            SYNCB();
        };
        #pragma clang loop unroll(disable)
        for (int k0 = 0; k0 < TTT + 8; k0 += 8) {
            step(IC<0>{},k0);   step(IC<1>{},k0+1); step(IC<2>{},k0+2); step(IC<3>{},k0+3);
            step(IC<4>{},k0+4); step(IC<5>{},k0+5); step(IC<6>{},k0+6); step(IC<7>{},k0+7);
        }
    }
}

extern "C" void kernel_launch(void* const* d_in, const int* in_sizes, int n_in,
                              void* d_out, int out_size, void* d_ws, size_t ws_size,
                              hipStream_t stream) {
    (void)in_sizes; (void)n_in; (void)d_ws; (void)ws_size; (void)out_size;
    const float* gx        = (const float*)d_in[0];
    const float* in_w      = (const float*)d_in[1];
    const float* in_b      = (const float*)d_in[2];
    const float* vad_wih   = (const float*)d_in[3];
    const float* vad_whh   = (const float*)d_in[4];
    const float* vad_bih   = (const float*)d_in[5];
    const float* vad_bhh   = (const float*)d_in[6];
    const float* vad_out_w = (const float*)d_in[7];
    const float* vad_out_b = (const float*)d_in[8];
    const float* noise_wih = (const float*)d_in[9];
    const float* noise_whh = (const float*)d_in[10];
    const float* noise_bih = (const float*)d_in[11];
    const float* noise_bhh = (const float*)d_in[12];
    const float* den_wih   = (const float*)d_in[13];
    const float* den_whh   = (const float*)d_in[14];
    const float* den_bih   = (const float*)d_in[15];
    const float* den_bhh   = (const float*)d_in[16];
    const float* out_w     = (const float*)d_in[17];
    const float* out_b     = (const float*)d_in[18];
    float* gains = (float*)d_out;
    float* vout  = (float*)d_out + (size_t)TB * (size_t)TTT * 22;

    rnnoise_kernel<<<dim3(TB), dim3(NTH), 0, stream>>>(
        gx, in_w, in_b, vad_wih, vad_whh, vad_bih, vad_bhh, vad_out_w, vad_out_b,
        noise_wih, noise_whh, noise_bih, noise_bhh, den_wih, den_whh, den_bih, den_bhh,
        out_w, out_b, gains, vout);
}

// Round 8
// 1724.727 us; speedup vs baseline: 1.1357x; 1.1357x over previous
//
#include <hip/hip_runtime.h>

typedef _Float16 f16;
typedef _Float16 h2 __attribute__((ext_vector_type(2)));
typedef unsigned int u32;

#define TB  256
#define TTT 2000
#define INW 42
#define HV  24
#define HN  48
#define HD  96
#define NTH 640

// act ring (depth 8), f16 regions per slot (all 16B-aligned):
// DIN [0,128):   vadh[0,24) | noih[24,72) | x[72,114) | pad       == den_wih col order
// DH  [128,224): denh
// NIN [224,320): tmp[224,248) | vadh[248,272) | x[272,314) | pad  == noise_wih col order
// NH  [320,384): noih[320,368) | pad
// Skews (tick k): vad t=k-1 | noise t=k-3 | den t=k-5 | out t=k-6.  h(t) in slot t&7.
// Input fragments for step t are READ one tick early (slot data complete >=1 tick
// before) and consumed from registers, hiding the post-barrier hh LDS latency.
#define DIN 0
#define DH  128
#define NIN 224
#define NH  320
#define ACTW 384

__device__ __forceinline__ float fsigm(float v) {
    return __builtin_amdgcn_rcpf(1.0f + __builtin_amdgcn_exp2f(-1.44269504089f * v));
}
__device__ __forceinline__ float ftanh(float v) {
    float e = __builtin_amdgcn_exp2f(2.88539008178f * v);
    return 1.0f - 2.0f * __builtin_amdgcn_rcpf(e + 1.0f);
}
__device__ __forceinline__ float dot2f(u32 a, u32 w, float c) {
#if __has_builtin(__builtin_amdgcn_fdot2)
    return __builtin_amdgcn_fdot2(__builtin_bit_cast(h2, a), __builtin_bit_cast(h2, w), c, false);
#else
    h2 av = __builtin_bit_cast(h2, a), wv = __builtin_bit_cast(h2, w);
    return c + (float)av[0] * (float)wv[0] + (float)av[1] * (float)wv[1];
#endif
}
__device__ __forceinline__ u32 packw(float a, float b) {
    h2 v; v[0] = (f16)a; v[1] = (f16)b;
    return __builtin_bit_cast(u32, v);
}
// DPP adds: xor quad_perm (0xB1,0x4E) direction-free; row_ror 0x124/0x128 only for
// full-row rotate-accumulate (every lane ends with the total, direction irrelevant).
template<int CTRL>
__device__ __forceinline__ float dpp_add(float x) {
    int y = __builtin_amdgcn_mov_dpp(__builtin_bit_cast(int, x), CTRL, 0xF, 0xF, true);
    return x + __builtin_bit_cast(float, y);
}

// raw barrier: flush LDS ops, do NOT drain vmcnt (x prefetch + global stores stay in flight)
#define SYNCB() asm volatile("s_waitcnt lgkmcnt(0)\n\ts_barrier" ::: "memory")

#define ACCI(AV, W, IDX) do { u32 _a = (AV); \
    rr = dot2f(_a, W[0][IDX], rr); zz = dot2f(_a, W[1][IDX], zz); an = dot2f(_a, W[2][IDX], an); } while (0)
#define ACCH(AV, W, IDX) do { u32 _a = (AV); \
    rr = dot2f(_a, W[0][IDX], rr); zz = dot2f(_a, W[1][IDX], zz); hn = dot2f(_a, W[2][IDX], hn); } while (0)
#define ACCI4(U4, W, M0) do { uint4 _u4 = (U4); \
    ACCI(_u4.x, W, (M0)+0); ACCI(_u4.y, W, (M0)+1); ACCI(_u4.z, W, (M0)+2); ACCI(_u4.w, W, (M0)+3); } while (0)
#define ACCH4(U4, W, M0) do { uint4 _u4 = (U4); \
    ACCH(_u4.x, W, (M0)+0); ACCH(_u4.y, W, (M0)+1); ACCH(_u4.z, W, (M0)+2); ACCH(_u4.w, W, (M0)+3); } while (0)
#define RED4_Q() do { \
    rr = dpp_add<0xB1>(rr); rr = dpp_add<0x4E>(rr); \
    zz = dpp_add<0xB1>(zz); zz = dpp_add<0x4E>(zz); \
    an = dpp_add<0xB1>(an); an = dpp_add<0x4E>(an); \
    hn = dpp_add<0xB1>(hn); hn = dpp_add<0x4E>(hn); } while (0)
#define RED4_1() do { \
    rr = dpp_add<0xB1>(rr); zz = dpp_add<0xB1>(zz); \
    an = dpp_add<0xB1>(an); hn = dpp_add<0xB1>(hn); } while (0)

template<int N> struct IC { static constexpr int val = N; };

__global__ __launch_bounds__(NTH, 1) void rnnoise_kernel(
    const float* __restrict__ gx,
    const float* __restrict__ in_w,      const float* __restrict__ in_b,
    const float* __restrict__ vad_wih,   const float* __restrict__ vad_whh,
    const float* __restrict__ vad_bih,   const float* __restrict__ vad_bhh,
    const float* __restrict__ vad_out_w, const float* __restrict__ vad_out_b,
    const float* __restrict__ noise_wih, const float* __restrict__ noise_whh,
    const float* __restrict__ noise_bih, const float* __restrict__ noise_bhh,
    const float* __restrict__ den_wih,   const float* __restrict__ den_whh,
    const float* __restrict__ den_bih,   const float* __restrict__ den_bhh,
    const float* __restrict__ out_w,     const float* __restrict__ out_b,
    float* __restrict__ gains, float* __restrict__ vout)
{
    __shared__ __align__(16) f16 act[8][ACTW];   // 6 KB

    const int tid = threadIdx.x, wid = tid >> 6, lane = tid & 63;
    const int b = blockIdx.x;

    // zero all slots (initial states AND pads)
    #pragma unroll
    for (int i = 0; i < 3; ++i) {
        int idx = tid + i * NTH;
        if (idx < 8 * ACTW / 2) ((u32*)act)[idx] = 0u;
    }
    __syncthreads();

    // SIMD-balanced role map (wid%4 round-robin assumption):
    // SIMD0 {0:den, 4:noise, 8:vad}  SIMD1 {1:den, 5:noise, 9:noise}
    // SIMD2 {2:den, 6:den+out(0..10)} SIMD3 {3:den, 7:den+out(11..21)}
    const int role = (wid == 8) ? 2 : ((wid == 4 || wid == 5 || wid == 9) ? 1 : 0);

    if (role == 0) {
        // ========== DEN waves: t = k-5; wid6/7 also OUT: t = k-6 ==========
        const int dwi = (wid < 4) ? wid : (wid - 2);       // 0..5
        const int u = 16 * dwi + (lane >> 2), q = lane & 3;
        const bool ow = (wid == 6 || wid == 7);
        const int o = ((wid == 7) ? 11 : 0) + (lane >> 2); // output band (ow only)
        const int oc = (ow && o < 22) ? o : 0;
        u32 wdi[3][16], wdh[3][12], wo[12];
        #pragma unroll
        for (int g = 0; g < 3; ++g) {
            const float* wi = den_wih + (g * HD + u) * 114;   // cols [vad|noi|x] == DIN order
            #pragma unroll
            for (int m = 0; m < 16; ++m) {
                int c = 32 * q + 2 * m;
                float a  = (c     < 114) ? wi[c]     : 0.f;
                float b2 = (c + 1 < 114) ? wi[c + 1] : 0.f;
                wdi[g][m] = packw(a, b2);
            }
            const float* wh = den_whh + (g * HD + u) * HD + 24 * q;
            #pragma unroll
            for (int m = 0; m < 12; ++m) wdh[g][m] = packw(wh[2*m], wh[2*m+1]);
        }
        #pragma unroll
        for (int m = 0; m < 12; ++m)
            wo[m] = ow ? packw(out_w[oc*HD + 24*q + 2*m], out_w[oc*HD + 24*q + 2*m + 1]) : 0u;
        const float bdr  = den_bih[u]        + den_bhh[u];
        const float bdz  = den_bih[HD + u]   + den_bhh[HD + u];
        const float bdni = den_bih[2*HD + u];
        const float bdnh = den_bhh[2*HD + u];
        const float bo   = ow ? out_b[oc] : 0.f;
        float hreg = 0.f;
        uint4 a0{}, a1{}, a2{}, a3{};   // input frags of step t, read one tick early

        auto step = [&](auto PC, int k) {
            constexpr int P   = decltype(PC)::val;
            constexpr int SHH = (P + 2) & 7;   // denh(k-6): hh operand AND out operand
            constexpr int SWR = (P + 3) & 7;   // write denh(k-5)
            constexpr int SNX = (P + 4) & 7;   // inputs of t=k-4 (refill for next tick)
            // issue hh read first; hide its latency under register input dots
            const uint4* hp = (const uint4*)&act[SHH][DH + 24 * q];
            uint4 h0 = hp[0], h1 = hp[1], h2 = hp[2];
            float rr = 0, zz = 0, an = 0, hn = 0;
            ACCI4(a0, wdi, 0); ACCI4(a1, wdi, 4); ACCI4(a2, wdi, 8); ACCI4(a3, wdi, 12);
            ACCH4(h0, wdh, 0); ACCH4(h1, wdh, 4); ACCH4(h2, wdh, 8);
            RED4_Q();
            if (k >= 5 && k < TTT + 5 && q == 0) {
                float r = fsigm(rr + bdr);
                float z = fsigm(zz + bdz);
                float n = ftanh(an + bdni + r * (hn + bdnh));
                hreg = z * (hreg - n) + n;
                act[SWR][DH + u] = (f16)hreg;
            }
            // refill input frags for next tick (t=k-4; slot complete since tick k-1)
            {
                const uint4* ip = (const uint4*)&act[SNX][DIN + 32 * q];
                a0 = ip[0]; a1 = ip[1]; a2 = ip[2]; a3 = ip[3];
            }
            // OUT: gains(t=k-6) over denh(k-6) — operand IS h0..h2 (same slice), free of LDS reads
            if (ow && k >= 6 && k < TTT + 6) {
                float acc = 0;
                acc = dot2f(h0.x, wo[0], acc);  acc = dot2f(h0.y, wo[1], acc);
                acc = dot2f(h0.z, wo[2], acc);  acc = dot2f(h0.w, wo[3], acc);
                acc = dot2f(h1.x, wo[4], acc);  acc = dot2f(h1.y, wo[5], acc);
                acc = dot2f(h1.z, wo[6], acc);  acc = dot2f(h1.w, wo[7], acc);
                acc = dot2f(h2.x, wo[8], acc);  acc = dot2f(h2.y, wo[9], acc);
                acc = dot2f(h2.z, wo[10], acc); acc = dot2f(h2.w, wo[11], acc);
                acc = dpp_add<0xB1>(acc); acc = dpp_add<0x4E>(acc);
                if (q == 0 && o < 22)
                    gains[((size_t)b * TTT + (k - 6)) * 22 + o] = fsigm(acc + bo);
            }
            SYNCB();
        };
        #pragma clang loop unroll(disable)
        for (int k0 = 0; k0 < TTT + 8; k0 += 8) {
            step(IC<0>{},k0);   step(IC<1>{},k0+1); step(IC<2>{},k0+2); step(IC<3>{},k0+3);
            step(IC<4>{},k0+4); step(IC<5>{},k0+5); step(IC<6>{},k0+6); step(IC<7>{},k0+7);
        }

    } else if (role == 1) {
        // ========== NOISE waves (wid 4,5,9): t = k-3 ==========
        const int nwi = (wid == 4) ? 0 : ((wid == 5) ? 1 : 2);
        const int u = 16 * nwi + (lane >> 2), q = lane & 3;
        u32 wni[3][12], wnh[3][8];
        #pragma unroll
        for (int g = 0; g < 3; ++g) {
            const float* wi = noise_wih + (g * HN + u) * 90;   // cols [tmp|vad|x] == NIN order
            #pragma unroll
            for (int m = 0; m < 12; ++m) {
                int c = 24 * q + 2 * m;
                float a  = (c     < 90) ? wi[c]     : 0.f;
                float b2 = (c + 1 < 90) ? wi[c + 1] : 0.f;
                wni[g][m] = packw(a, b2);
            }
            const float* wh = noise_whh + (g * HN + u) * HN;
            #pragma unroll
            for (int m = 0; m < 8; ++m) {
                int c = 16 * q + 2 * m;                        // NH dim (pad -> 0 weight)
                float a  = (c     < 48) ? wh[c]     : 0.f;
                float b2 = (c + 1 < 48) ? wh[c + 1] : 0.f;
                wnh[g][m] = packw(a, b2);
            }
        }
        const float bnr  = noise_bih[u]        + noise_bhh[u];
        const float bnz  = noise_bih[HN + u]   + noise_bhh[HN + u];
        const float bnni = noise_bih[2*HN + u];
        const float bnnh = noise_bhh[2*HN + u];
        float hreg = 0.f;
        uint4 a0{}, a1{}, a2{};   // input frags, read one tick early

        auto step = [&](auto PC, int k) {
            constexpr int P   = decltype(PC)::val;
            constexpr int SHH = (P + 4) & 7;   // noih(k-4)
            constexpr int SWR = (P + 5) & 7;   // write noih(k-3)
            constexpr int SNX = (P + 6) & 7;   // inputs of t=k-2 (refill for next tick)
            const uint4* hp = (const uint4*)&act[SHH][NH + 16 * q];
            uint4 h0 = hp[0], h1 = hp[1];
            float rr = 0, zz = 0, an = 0, hn = 0;
            ACCI4(a0, wni, 0); ACCI4(a1, wni, 4); ACCI4(a2, wni, 8);
            ACCH4(h0, wnh, 0); ACCH4(h1, wnh, 4);
            RED4_Q();
            if (k >= 3 && k < TTT + 3 && q == 0) {
                float r = fsigm(rr + bnr);
                float z = fsigm(zz + bnz);
                float n = ftanh(an + bnni + r * (hn + bnnh));
                hreg = z * (hreg - n) + n;
                f16 hh = (f16)hreg;
                act[SWR][NH + u]       = hh;   // noise hh source
                act[SWR][DIN + 24 + u] = hh;   // den input copy
            }
            {
                const uint4* ip = (const uint4*)&act[SNX][NIN + 24 * q];
                a0 = ip[0]; a1 = ip[1]; a2 = ip[2];
            }
            SYNCB();
        };
        #pragma clang loop unroll(disable)
        for (int k0 = 0; k0 < TTT + 8; k0 += 8) {
            step(IC<0>{},k0);   step(IC<1>{},k0+1); step(IC<2>{},k0+2); step(IC<3>{},k0+3);
            step(IC<4>{},k0+4); step(IC<5>{},k0+5); step(IC<6>{},k0+6); step(IC<7>{},k0+7);
        }

    } else {
        // ========== VAD wave (wid 8): x stage + tmp(k) + vad GRU(t=k-1) + vad_out(t=k-1) ==========
        const int l = lane;
        const int u = (l < 48) ? (l >> 1) : 0, q2 = l & 1;
        u32 wvi[3][6], wvh[3][6], wtm[12];
        float bvr = 0, bvz = 0, bvni = 0, bvnh = 0, btm = 0, wvo_u = 0;
        if (l < 48) {
            #pragma unroll
            for (int g = 0; g < 3; ++g) {
                const float* wi = vad_wih + (g * HV + u) * HV + 12 * q2;
                const float* wh = vad_whh + (g * HV + u) * HV + 12 * q2;
                #pragma unroll
                for (int j = 0; j < 6; ++j) {
                    wvi[g][j] = packw(wi[2*j], wi[2*j+1]);
                    wvh[g][j] = packw(wh[2*j], wh[2*j+1]);
                }
            }
            #pragma unroll
            for (int j = 0; j < 12; ++j) {
                int c0 = 24 * q2 + 2 * j;
                float a = (c0     < INW) ? in_w[u * INW + c0]     : 0.f;
                float c = (c0 + 1 < INW) ? in_w[u * INW + c0 + 1] : 0.f;
                wtm[j] = packw(a, c);
            }
            bvr  = vad_bih[u]        + vad_bhh[u];
            bvz  = vad_bih[HV + u]   + vad_bhh[HV + u];
            bvni = vad_bih[2*HV + u];
            bvnh = vad_bhh[2*HV + u];
            btm  = in_b[u];
            if (q2 == 0) wvo_u = vad_out_w[u];
        }
        const float bvo = vad_out_b[0];
        float hreg = 0.f;

        float xa = 0, xb = 0, xc = 0, xd = 0;   // 4-deep x prefetch (reg chosen by P&3)
        if (l < INW) {
            xa = gx[((size_t)b * TTT + 0) * INW + l];
            xb = gx[((size_t)b * TTT + 1) * INW + l];
            xc = gx[((size_t)b * TTT + 2) * INW + l];
            xd = gx[((size_t)b * TTT + 3) * INW + l];
        }

        auto step = [&](auto PC, int k) {
            constexpr int P  = decltype(PC)::val;
            constexpr int ST = (P + 7) & 7;   // slot of t=k-1 (tmp read, vadh write)
            constexpr int SH = (P + 6) & 7;   // vadh(k-2)
            if (k < TTT && l < INW) {         // stage x(k) into both regions of slot P
                float xv;
                if constexpr ((P & 3) == 0) xv = xa; else if constexpr ((P & 3) == 1) xv = xb;
                else if constexpr ((P & 3) == 2) xv = xc; else xv = xd;
                f16 xh = (f16)xv;
                act[P][NIN + 48 + l] = xh;
                act[P][DIN + 72 + l] = xh;
            }
            if (k + 4 < TTT && l < INW) {     // refill phase register with x(k+4)
                float xv = gx[((size_t)b * TTT + (k + 4)) * INW + l];
                if constexpr ((P & 3) == 0) xa = xv; else if constexpr ((P & 3) == 1) xb = xv;
                else if constexpr ((P & 3) == 2) xc = xv; else xd = xv;
            }
            if (k >= 1 && k <= TTT) {         // vad GRU t = k-1
                float rr = 0, zz = 0, an = 0, hn = 0;
                if (l < 48) {
                    const uint2* tp = (const uint2*)&act[ST][NIN + 12 * q2];       // tmp(t)
                    const uint2* hp = (const uint2*)&act[SH][NIN + 24 + 12 * q2];  // vadh(t-1)
                    #pragma unroll
                    for (int v = 0; v < 3; ++v) {
                        uint2 a = tp[v]; ACCI(a.x, wvi, 2*v); ACCI(a.y, wvi, 2*v+1);
                        uint2 h = hp[v]; ACCH(h.x, wvh, 2*v); ACCH(h.y, wvh, 2*v+1);
                    }
                    RED4_1();
                    if (q2 == 0) {
                        float r = fsigm(rr + bvr);
                        float z = fsigm(zz + bvz);
                        float n = ftanh(an + bvni + r * (hn + bvnh));
                        hreg = z * (hreg - n) + n;
                        f16 hh = (f16)hreg;
                        act[ST][NIN + 24 + u] = hh;   // noise/vad hh source
                        act[ST][DIN + u]      = hh;   // den input copy
                    }
                }
                float val = (l < 48 && q2 == 0) ? (wvo_u * hreg) : 0.f;
                val = dpp_add<0xB1>(val);  val = dpp_add<0x4E>(val);
                val = dpp_add<0x124>(val); val = dpp_add<0x128>(val);   // full 16-row sum
                val += __shfl_xor(val, 16); val += __shfl_xor(val, 32);
                if (l == 0) vout[(size_t)b * TTT + (k - 1)] = fsigm(val + bvo);
            }
            if (k < TTT && l < 48) {          // tmp(k) from x(k) staged this tick (intra-wave)
                float acc = 0;
                const uint4* xp = (const uint4*)&act[P][NIN + 48 + 24 * q2];
                uint4 a = xp[0], b2 = xp[1], c2 = xp[2];
                acc = dot2f(a.x,  wtm[0], acc);  acc = dot2f(a.y,  wtm[1], acc);
                acc = dot2f(a.z,  wtm[2], acc);  acc = dot2f(a.w,  wtm[3], acc);
                acc = dot2f(b2.x, wtm[4], acc);  acc = dot2f(b2.y, wtm[5], acc);
                acc = dot2f(b2.z, wtm[6], acc);  acc = dot2f(b2.w, wtm[7], acc);
                acc = dot2f(c2.x, wtm[8], acc);  acc = dot2f(c2.y, wtm[9], acc);
                acc = dot2f(c2.z, wtm[10], acc); acc = dot2f(c2.w, wtm[11], acc);
                acc = dpp_add<0xB1>(acc);
                if (q2 == 0) act[P][NIN + u] = (f16)ftanh(acc + btm);
            }
            SYNCB();
        };
        #pragma clang loop unroll(disable)
        for (int k0 = 0; k0 < TTT + 8; k0 += 8) {
            step(IC<0>{},k0);   step(IC<1>{},k0+1); step(IC<2>{},k0+2); step(IC<3>{},k0+3);
            step(IC<4>{},k0+4); step(IC<5>{},k0+5); step(IC<6>{},k0+6); step(IC<7>{},k0+7);
        }
    }
}

extern "C" void kernel_launch(void* const* d_in, const int* in_sizes, int n_in,
                              void* d_out, int out_size, void* d_ws, size_t ws_size,
                              hipStream_t stream) {
    (void)in_sizes; (void)n_in; (void)d_ws; (void)ws_size; (void)out_size;
    const float* gx        = (const float*)d_in[0];
    const float* in_w      = (const float*)d_in[1];
    const float* in_b      = (const float*)d_in[2];
    const float* vad_wih   = (const float*)d_in[3];
    const float* vad_whh   = (const float*)d_in[4];
    const float* vad_bih   = (const float*)d_in[5];
    const float* vad_bhh   = (const float*)d_in[6];
    const float* vad_out_w = (const float*)d_in[7];
    const float* vad_out_b = (const float*)d_in[8];
    const float* noise_wih = (const float*)d_in[9];
    const float* noise_whh = (const float*)d_in[10];
    const float* noise_bih = (const float*)d_in[11];
    const float* noise_bhh = (const float*)d_in[12];
    const float* den_wih   = (const float*)d_in[13];
    const float* den_whh   = (const float*)d_in[14];
    const float* den_bih   = (const float*)d_in[15];
    const float* den_bhh   = (const float*)d_in[16];
    const float* out_w     = (const float*)d_in[17];
    const float* out_b     = (const float*)d_in[18];
    float* gains = (float*)d_out;
    float* vout  = (float*)d_out + (size_t)TB * (size_t)TTT * 22;

    rnnoise_kernel<<<dim3(TB), dim3(NTH), 0, stream>>>(
        gx, in_w, in_b, vad_wih, vad_whh, vad_bih, vad_bhh, vad_out_w, vad_out_b,
        noise_wih, noise_whh, noise_bih, noise_bhh, den_wih, den_whh, den_bih, den_bhh,
        out_w, out_b, gains, vout);
}

// Round 10
// 1638.737 us; speedup vs baseline: 1.1953x; 1.0525x over previous
//
#include <hip/hip_runtime.h>

typedef _Float16 f16;
typedef _Float16 h2 __attribute__((ext_vector_type(2)));
typedef unsigned int u32;

#define TB  256
#define TTT 2000
#define INW 42
#define HV  24
#define HN  48
#define HD  96
#define NTH 640

// act ring (depth 8), f16 regions per slot (all 16B-aligned):
// DIN [0,128):   vadh[0,24) | noih[24,72) | x[72,114) | pad       == den_wih col order
// DH  [128,224): denh
// NIN [224,320): tmp[224,248) | vadh[248,272) | x[272,314) | pad  == noise_wih col order
// NH  [320,384): noih[320,368) | pad
// Skews (tick k): vad t=k-1 | noise t=k-3 | den t=k-5 | out t=k-6.  h(t) in slot t&7.
// ONE barrier per tick (structural: the hh recurrence is a gap-1 cross-wave edge).
// x(k+1) is staged at tick k (one tick early) so tmp(k+1)'s LDS read has a full
// tick + barrier-drain of latency cover. Input frags read one tick early into regs.
#define DIN 0
#define DH  128
#define NIN 224
#define NH  320
#define ACTW 384

__device__ __forceinline__ float fsigm(float v) {
    return __builtin_amdgcn_rcpf(1.0f + __builtin_amdgcn_exp2f(-1.44269504089f * v));
}
__device__ __forceinline__ float ftanh(float v) {
    float e = __builtin_amdgcn_exp2f(2.88539008178f * v);
    return 1.0f - 2.0f * __builtin_amdgcn_rcpf(e + 1.0f);
}
__device__ __forceinline__ float dot2f(u32 a, u32 w, float c) {
#if __has_builtin(__builtin_amdgcn_fdot2)
    return __builtin_amdgcn_fdot2(__builtin_bit_cast(h2, a), __builtin_bit_cast(h2, w), c, false);
#else
    h2 av = __builtin_bit_cast(h2, a), wv = __builtin_bit_cast(h2, w);
    return c + (float)av[0] * (float)wv[0] + (float)av[1] * (float)wv[1];
#endif
}
__device__ __forceinline__ u32 packw(float a, float b) {
    h2 v; v[0] = (f16)a; v[1] = (f16)b;
    return __builtin_bit_cast(u32, v);
}
// DPP adds: xor quad_perm (0xB1,0x4E) direction-free; row_ror 0x124/0x128 full-row
// rotate-accumulate (every lane ends with its row total, direction irrelevant).
template<int CTRL>
__device__ __forceinline__ float dpp_add(float x) {
    int y = __builtin_amdgcn_mov_dpp(__builtin_bit_cast(int, x), CTRL, 0xF, 0xF, true);
    return x + __builtin_bit_cast(float, y);
}
// masked DPP add for row_bcast steps: masked-off rows add 0 (update_dpp old=0).
template<int CTRL, int RMASK>
__device__ __forceinline__ float dpp_add_m(float x) {
    int y = __builtin_amdgcn_update_dpp(0, __builtin_bit_cast(int, x), CTRL, RMASK, 0xF, false);
    return x + __builtin_bit_cast(float, y);
}

// raw barrier: flush LDS ops, do NOT drain vmcnt (x prefetch + global stores stay in flight)
#define SYNCB() asm volatile("s_waitcnt lgkmcnt(0)\n\ts_barrier" ::: "memory")

#define ACCI(AV, W, IDX) do { u32 _a = (AV); \
    rr = dot2f(_a, W[0][IDX], rr); zz = dot2f(_a, W[1][IDX], zz); an = dot2f(_a, W[2][IDX], an); } while (0)
#define ACCH(AV, W, IDX) do { u32 _a = (AV); \
    rr = dot2f(_a, W[0][IDX], rr); zz = dot2f(_a, W[1][IDX], zz); hn = dot2f(_a, W[2][IDX], hn); } while (0)
#define ACCI4(U4, W, M0) do { uint4 _u4 = (U4); \
    ACCI(_u4.x, W, (M0)+0); ACCI(_u4.y, W, (M0)+1); ACCI(_u4.z, W, (M0)+2); ACCI(_u4.w, W, (M0)+3); } while (0)
#define ACCH4(U4, W, M0) do { uint4 _u4 = (U4); \
    ACCH(_u4.x, W, (M0)+0); ACCH(_u4.y, W, (M0)+1); ACCH(_u4.z, W, (M0)+2); ACCH(_u4.w, W, (M0)+3); } while (0)
#define RED4_Q() do { \
    rr = dpp_add<0xB1>(rr); rr = dpp_add<0x4E>(rr); \
    zz = dpp_add<0xB1>(zz); zz = dpp_add<0x4E>(zz); \
    an = dpp_add<0xB1>(an); an = dpp_add<0x4E>(an); \
    hn = dpp_add<0xB1>(hn); hn = dpp_add<0x4E>(hn); } while (0)
#define RED4_1() do { \
    rr = dpp_add<0xB1>(rr); zz = dpp_add<0xB1>(zz); \
    an = dpp_add<0xB1>(an); hn = dpp_add<0xB1>(hn); } while (0)

template<int N> struct IC { static constexpr int val = N; };

__global__ __launch_bounds__(NTH, 1) void rnnoise_kernel(
    const float* __restrict__ gx,
    const float* __restrict__ in_w,      const float* __restrict__ in_b,
    const float* __restrict__ vad_wih,   const float* __restrict__ vad_whh,
    const float* __restrict__ vad_bih,   const float* __restrict__ vad_bhh,
    const float* __restrict__ vad_out_w, const float* __restrict__ vad_out_b,
    const float* __restrict__ noise_wih, const float* __restrict__ noise_whh,
    const float* __restrict__ noise_bih, const float* __restrict__ noise_bhh,
    const float* __restrict__ den_wih,   const float* __restrict__ den_whh,
    const float* __restrict__ den_bih,   const float* __restrict__ den_bhh,
    const float* __restrict__ out_w,     const float* __restrict__ out_b,
    float* __restrict__ gains, float* __restrict__ vout)
{
    __shared__ __align__(16) f16 act[8][ACTW];   // 6 KB

    const int tid = threadIdx.x, wid = tid >> 6, lane = tid & 63;
    const int b = blockIdx.x;

    // zero all slots (initial states AND pads)
    #pragma unroll
    for (int i = 0; i < 3; ++i) {
        int idx = tid + i * NTH;
        if (idx < 8 * ACTW / 2) ((u32*)act)[idx] = 0u;
    }
    __syncthreads();

    // SIMD-balanced role map (wid%4 round-robin assumption):
    // SIMD0 {0:den, 4:noise, 8:vad}  SIMD1 {1:den, 5:noise, 9:noise}
    // SIMD2 {2:den, 6:den+out(0..10)} SIMD3 {3:den, 7:den+out(11..21)}
    const int role = (wid == 8) ? 2 : ((wid == 4 || wid == 5 || wid == 9) ? 1 : 0);

    if (role == 0) {
        // ========== DEN waves: t = k-5; wid6/7 also OUT: t = k-6 ==========
        const int dwi = (wid < 4) ? wid : (wid - 2);       // 0..5
        const int u = 16 * dwi + (lane >> 2), q = lane & 3;
        const bool ow = (wid == 6 || wid == 7);
        const int o = ((wid == 7) ? 11 : 0) + (lane >> 2); // output band (ow only)
        const int oc = (ow && o < 22) ? o : 0;
        u32 wdi[3][16], wdh[3][12], wo[12];
        #pragma unroll
        for (int g = 0; g < 3; ++g) {
            const float* wi = den_wih + (g * HD + u) * 114;   // cols [vad|noi|x] == DIN order
            #pragma unroll
            for (int m = 0; m < 16; ++m) {
                int c = 32 * q + 2 * m;
                float a  = (c     < 114) ? wi[c]     : 0.f;
                float b2 = (c + 1 < 114) ? wi[c + 1] : 0.f;
                wdi[g][m] = packw(a, b2);
            }
            const float* wh = den_whh + (g * HD + u) * HD + 24 * q;
            #pragma unroll
            for (int m = 0; m < 12; ++m) wdh[g][m] = packw(wh[2*m], wh[2*m+1]);
        }
        #pragma unroll
        for (int m = 0; m < 12; ++m)
            wo[m] = ow ? packw(out_w[oc*HD + 24*q + 2*m], out_w[oc*HD + 24*q + 2*m + 1]) : 0u;
        const float bdr  = den_bih[u]        + den_bhh[u];
        const float bdz  = den_bih[HD + u]   + den_bhh[HD + u];
        const float bdni = den_bih[2*HD + u];
        const float bdnh = den_bhh[2*HD + u];
        const float bo   = ow ? out_b[oc] : 0.f;
        float hreg = 0.f;
        uint4 a0{}, a1{}, a2{}, a3{};   // input frags of step t, read one tick early

        auto step = [&](auto PC, int k) {
            constexpr int P   = decltype(PC)::val;
            constexpr int SHH = (P + 2) & 7;   // denh(k-6): hh operand AND out operand
            constexpr int SWR = (P + 3) & 7;   // write denh(k-5)
            constexpr int SNX = (P + 4) & 7;   // inputs of t=k-4 (refill for next tick)
            // issue hh read first; hide its latency under register input dots
            const uint4* hp = (const uint4*)&act[SHH][DH + 24 * q];
            uint4 h0 = hp[0], h1 = hp[1], h2 = hp[2];
            float rr = 0, zz = 0, an = 0, hn = 0;
            ACCI4(a0, wdi, 0); ACCI4(a1, wdi, 4); ACCI4(a2, wdi, 8); ACCI4(a3, wdi, 12);
            ACCH4(h0, wdh, 0); ACCH4(h1, wdh, 4); ACCH4(h2, wdh, 8);
            RED4_Q();
            if (k >= 5 && k < TTT + 5 && q == 0) {
                float r = fsigm(rr + bdr);
                float z = fsigm(zz + bdz);
                float n = ftanh(an + bdni + r * (hn + bdnh));
                hreg = z * (hreg - n) + n;
                act[SWR][DH + u] = (f16)hreg;
            }
            // refill input frags for next tick (t=k-4; slot writers all >=1 barrier old)
            {
                const uint4* ip = (const uint4*)&act[SNX][DIN + 32 * q];
                a0 = ip[0]; a1 = ip[1]; a2 = ip[2]; a3 = ip[3];
            }
            // OUT: gains(t=k-6) over denh(k-6) — operand IS h0..h2 (same slice), no extra LDS
            if (ow && k >= 6 && k < TTT + 6) {
                float acc = 0;
                acc = dot2f(h0.x, wo[0], acc);  acc = dot2f(h0.y, wo[1], acc);
                acc = dot2f(h0.z, wo[2], acc);  acc = dot2f(h0.w, wo[3], acc);
                acc = dot2f(h1.x, wo[4], acc);  acc = dot2f(h1.y, wo[5], acc);
                acc = dot2f(h1.z, wo[6], acc);  acc = dot2f(h1.w, wo[7], acc);
                acc = dot2f(h2.x, wo[8], acc);  acc = dot2f(h2.y, wo[9], acc);
                acc = dot2f(h2.z, wo[10], acc); acc = dot2f(h2.w, wo[11], acc);
                acc = dpp_add<0xB1>(acc); acc = dpp_add<0x4E>(acc);
                if (q == 0 && o < 22)
                    gains[((size_t)b * TTT + (k - 6)) * 22 + o] = fsigm(acc + bo);
            }
            SYNCB();
        };
        #pragma clang loop unroll(disable)
        for (int k0 = 0; k0 < TTT + 8; k0 += 8) {
            step(IC<0>{},k0);   step(IC<1>{},k0+1); step(IC<2>{},k0+2); step(IC<3>{},k0+3);
            step(IC<4>{},k0+4); step(IC<5>{},k0+5); step(IC<6>{},k0+6); step(IC<7>{},k0+7);
        }

    } else if (role == 1) {
        // ========== NOISE waves (wid 4,5,9): t = k-3 ==========
        const int nwi = (wid == 4) ? 0 : ((wid == 5) ? 1 : 2);
        const int u = 16 * nwi + (lane >> 2), q = lane & 3;
        u32 wni[3][12], wnh[3][8];
        #pragma unroll
        for (int g = 0; g < 3; ++g) {
            const float* wi = noise_wih + (g * HN + u) * 90;   // cols [tmp|vad|x] == NIN order
            #pragma unroll
            for (int m = 0; m < 12; ++m) {
                int c = 24 * q + 2 * m;
                float a  = (c     < 90) ? wi[c]     : 0.f;
                float b2 = (c + 1 < 90) ? wi[c + 1] : 0.f;
                wni[g][m] = packw(a, b2);
            }
            const float* wh = noise_whh + (g * HN + u) * HN;
            #pragma unroll
            for (int m = 0; m < 8; ++m) {
                int c = 16 * q + 2 * m;                        // NH dim (pad -> 0 weight)
                float a  = (c     < 48) ? wh[c]     : 0.f;
                float b2 = (c + 1 < 48) ? wh[c + 1] : 0.f;
                wnh[g][m] = packw(a, b2);
            }
        }
        const float bnr  = noise_bih[u]        + noise_bhh[u];
        const float bnz  = noise_bih[HN + u]   + noise_bhh[HN + u];
        const float bnni = noise_bih[2*HN + u];
        const float bnnh = noise_bhh[2*HN + u];
        float hreg = 0.f;
        uint4 a0{}, a1{}, a2{};   // input frags, read one tick early

        auto step = [&](auto PC, int k) {
            constexpr int P   = decltype(PC)::val;
            constexpr int SHH = (P + 4) & 7;   // noih(k-4)
            constexpr int SWR = (P + 5) & 7;   // write noih(k-3)
            constexpr int SNX = (P + 6) & 7;   // inputs of t=k-2 (refill for next tick)
            const uint4* hp = (const uint4*)&act[SHH][NH + 16 * q];
            uint4 h0 = hp[0], h1 = hp[1];
            float rr = 0, zz = 0, an = 0, hn = 0;
            ACCI4(a0, wni, 0); ACCI4(a1, wni, 4); ACCI4(a2, wni, 8);
            ACCH4(h0, wnh, 0); ACCH4(h1, wnh, 4);
            RED4_Q();
            if (k >= 3 && k < TTT + 3 && q == 0) {
                float r = fsigm(rr + bnr);
                float z = fsigm(zz + bnz);
                float n = ftanh(an + bnni + r * (hn + bnnh));
                hreg = z * (hreg - n) + n;
                f16 hh = (f16)hreg;
                act[SWR][NH + u]       = hh;   // noise hh source
                act[SWR][DIN + 24 + u] = hh;   // den input copy
            }
            {
                const uint4* ip = (const uint4*)&act[SNX][NIN + 24 * q];
                a0 = ip[0]; a1 = ip[1]; a2 = ip[2];
            }
            SYNCB();
        };
        #pragma clang loop unroll(disable)
        for (int k0 = 0; k0 < TTT + 8; k0 += 8) {
            step(IC<0>{},k0);   step(IC<1>{},k0+1); step(IC<2>{},k0+2); step(IC<3>{},k0+3);
            step(IC<4>{},k0+4); step(IC<5>{},k0+5); step(IC<6>{},k0+6); step(IC<7>{},k0+7);
        }

    } else {
        // ========== VAD wave (wid 8): x(k+1) stage + tmp(k) + vad GRU(t=k-1) + vad_out(t=k-1) ==========
        const int l = lane;
        const int u = (l < 48) ? (l >> 1) : 0, q2 = l & 1;
        u32 wvi[3][6], wvh[3][6], wtm[12];
        float bvr = 0, bvz = 0, bvni = 0, bvnh = 0, btm = 0, wvo_u = 0;
        if (l < 48) {
            #pragma unroll
            for (int g = 0; g < 3; ++g) {
                const float* wi = vad_wih + (g * HV + u) * HV + 12 * q2;
                const float* wh = vad_whh + (g * HV + u) * HV + 12 * q2;
                #pragma unroll
                for (int j = 0; j < 6; ++j) {
                    wvi[g][j] = packw(wi[2*j], wi[2*j+1]);
                    wvh[g][j] = packw(wh[2*j], wh[2*j+1]);
                }
            }
            #pragma unroll
            for (int j = 0; j < 12; ++j) {
                int c0 = 24 * q2 + 2 * j;
                float a = (c0     < INW) ? in_w[u * INW + c0]     : 0.f;
                float c = (c0 + 1 < INW) ? in_w[u * INW + c0 + 1] : 0.f;
                wtm[j] = packw(a, c);
            }
            bvr  = vad_bih[u]        + vad_bhh[u];
            bvz  = vad_bih[HV + u]   + vad_bhh[HV + u];
            bvni = vad_bih[2*HV + u];
            bvnh = vad_bhh[2*HV + u];
            btm  = in_b[u];
            if (q2 == 0) wvo_u = vad_out_w[u];
        }
        const float bvo = vad_out_b[0];
        float hreg = 0.f;

        // prologue: reg r = t&3 holds x(t) at staging time.
        // stage x(0) NOW (after init sync); regs hold x(1..4).
        float xa = 0, xb = 0, xc = 0, xd = 0;
        if (l < INW) {
            float x0v = gx[((size_t)b * TTT + 0) * INW + l];
            xb = gx[((size_t)b * TTT + 1) * INW + l];
            xc = gx[((size_t)b * TTT + 2) * INW + l];
            xd = gx[((size_t)b * TTT + 3) * INW + l];
            xa = gx[((size_t)b * TTT + 4) * INW + l];
            f16 xh = (f16)x0v;
            act[0][NIN + 48 + l] = xh;
            act[0][DIN + 72 + l] = xh;
        }

        auto step = [&](auto PC, int k) {
            constexpr int P  = decltype(PC)::val;
            constexpr int SX = (P + 1) & 7;   // stage x(k+1) one tick early
            constexpr int ST = (P + 7) & 7;   // slot of t=k-1 (tmp read, vadh write)
            constexpr int SH = (P + 6) & 7;   // vadh(k-2)
            constexpr int XR = (P + 1) & 3;   // x phase register index for x(k+1)
            if (k + 1 < TTT && l < INW) {     // stage x(k+1) into both regions of slot SX
                float xv;
                if constexpr (XR == 0) xv = xa; else if constexpr (XR == 1) xv = xb;
                else if constexpr (XR == 2) xv = xc; else xv = xd;
                f16 xh = (f16)xv;
                act[SX][NIN + 48 + l] = xh;
                act[SX][DIN + 72 + l] = xh;
            }
            if (k + 5 < TTT && l < INW) {     // refill phase register with x(k+5)
                float xv = gx[((size_t)b * TTT + (k + 5)) * INW + l];
                if constexpr (XR == 0) xa = xv; else if constexpr (XR == 1) xb = xv;
                else if constexpr (XR == 2) xc = xv; else xd = xv;
            }
            if (k >= 1 && k <= TTT) {         // vad GRU t = k-1
                float rr = 0, zz = 0, an = 0, hn = 0;
                if (l < 48) {
                    const uint2* tp = (const uint2*)&act[ST][NIN + 12 * q2];       // tmp(t)
                    const uint2* hp = (const uint2*)&act[SH][NIN + 24 + 12 * q2];  // vadh(t-1)
                    #pragma unroll
                    for (int v = 0; v < 3; ++v) {
                        uint2 a = tp[v]; ACCI(a.x, wvi, 2*v); ACCI(a.y, wvi, 2*v+1);
                        uint2 h = hp[v]; ACCH(h.x, wvh, 2*v); ACCH(h.y, wvh, 2*v+1);
                    }
                    RED4_1();
                    if (q2 == 0) {
                        float r = fsigm(rr + bvr);
                        float z = fsigm(zz + bvz);
                        float n = ftanh(an + bvni + r * (hn + bvnh));
                        hreg = z * (hreg - n) + n;
                        f16 hh = (f16)hreg;
                        act[ST][NIN + 24 + u] = hh;   // noise/vad hh source
                        act[ST][DIN + u]      = hh;   // den input copy
                    }
                }
                // vad_out(t): all-DPP full-wave reduce (no ds_bpermute).
                // quad xor -> full-row ror (row totals) -> masked row_bcast15/31; lane 63 holds total.
                float val = (l < 48 && q2 == 0) ? (wvo_u * hreg) : 0.f;
                val = dpp_add<0xB1>(val);  val = dpp_add<0x4E>(val);
                val = dpp_add<0x124>(val); val = dpp_add<0x128>(val);     // row totals
                val = dpp_add_m<0x142, 0xA>(val);   // rows 1,3 += prev row's lane15/47
                val = dpp_add_m<0x143, 0xC>(val);   // rows 2,3 += lane31 (T0+T1)
                if (l == 63) vout[(size_t)b * TTT + (k - 1)] = fsigm(val + bvo);
            }
            if (k < TTT && l < 48) {          // tmp(k) from x(k) staged LAST tick (full-tick latency cover)
                float acc = 0;
                const uint4* xp = (const uint4*)&act[P][NIN + 48 + 24 * q2];
                uint4 a = xp[0], b2 = xp[1], c2 = xp[2];
                acc = dot2f(a.x,  wtm[0], acc);  acc = dot2f(a.y,  wtm[1], acc);
                acc = dot2f(a.z,  wtm[2], acc);  acc = dot2f(a.w,  wtm[3], acc);
                acc = dot2f(b2.x, wtm[4], acc);  acc = dot2f(b2.y, wtm[5], acc);
                acc = dot2f(b2.z, wtm[6], acc);  acc = dot2f(b2.w, wtm[7], acc);
                acc = dot2f(c2.x, wtm[8], acc);  acc = dot2f(c2.y, wtm[9], acc);
                acc = dot2f(c2.z, wtm[10], acc); acc = dot2f(c2.w, wtm[11], acc);
                acc = dpp_add<0xB1>(acc);
                if (q2 == 0) act[P][NIN + u] = (f16)ftanh(acc + btm);
            }
            SYNCB();
        };
        #pragma clang loop unroll(disable)
        for (int k0 = 0; k0 < TTT + 8; k0 += 8) {
            step(IC<0>{},k0);   step(IC<1>{},k0+1); step(IC<2>{},k0+2); step(IC<3>{},k0+3);
            step(IC<4>{},k0+4); step(IC<5>{},k0+5); step(IC<6>{},k0+6); step(IC<7>{},k0+7);
        }
    }
}

extern "C" void kernel_launch(void* const* d_in, const int* in_sizes, int n_in,
                              void* d_out, int out_size, void* d_ws, size_t ws_size,
                              hipStream_t stream) {
    (void)in_sizes; (void)n_in; (void)d_ws; (void)ws_size; (void)out_size;
    const float* gx        = (const float*)d_in[0];
    const float* in_w      = (const float*)d_in[1];
    const float* in_b      = (const float*)d_in[2];
    const float* vad_wih   = (const float*)d_in[3];
    const float* vad_whh   = (const float*)d_in[4];
    const float* vad_bih   = (const float*)d_in[5];
    const float* vad_bhh   = (const float*)d_in[6];
    const float* vad_out_w = (const float*)d_in[7];
    const float* vad_out_b = (const float*)d_in[8];
    const float* noise_wih = (const float*)d_in[9];
    const float* noise_whh = (const float*)d_in[10];
    const float* noise_bih = (const float*)d_in[11];
    const float* noise_bhh = (const float*)d_in[12];
    const float* den_wih   = (const float*)d_in[13];
    const float* den_whh   = (const float*)d_in[14];
    const float* den_bih   = (const float*)d_in[15];
    const float* den_bhh   = (const float*)d_in[16];
    const float* out_w     = (const float*)d_in[17];
    const float* out_b     = (const float*)d_in[18];
    float* gains = (float*)d_out;
    float* vout  = (float*)d_out + (size_t)TB * (size_t)TTT * 22;

    rnnoise_kernel<<<dim3(TB), dim3(NTH), 0, stream>>>(
        gx, in_w, in_b, vad_wih, vad_whh, vad_bih, vad_bhh, vad_out_w, vad_out_b,
        noise_wih, noise_whh, noise_bih, noise_bhh, den_wih, den_whh, den_bih, den_bhh,
        out_w, out_b, gains, vout);
}

// Round 11
// 1576.687 us; speedup vs baseline: 1.2423x; 1.0394x over previous
//
#include <hip/hip_runtime.h>

typedef _Float16 f16;
typedef _Float16 h2 __attribute__((ext_vector_type(2)));
typedef unsigned int u32;

#define TB  256
#define TTT 2000
#define INW 42
#define HV  24
#define HN  48
#define HD  96
#define NTH 640

// act ring (depth 8), f16 regions per slot (all 16B-aligned):
// DIN [0,128):   vadh[0,24) | noih[24,72) | x[72,114) | pad       == den_wih col order
// DH  [128,224): denh
// NIN [224,320): tmp[224,248) | vadh[248,272) | x[272,314) | pad  == noise_wih col order
// NH  [320,384): noih[320,368) | pad
// Skews (tick k): vad t=k-1 | noise t=k-3 | den t=k-5 | out t=k-6.  h(t) in slot t&7.
// ONE barrier per tick (hh recurrence is a gap-1 cross-wave edge — r9 lesson).
// Guard peeling: steady ticks k in [16, TTT-16) compile with zero k-branches.
#define DIN 0
#define DH  128
#define NIN 224
#define NH  320
#define ACTW 384

__device__ __forceinline__ float fsigm(float v) {
    return __builtin_amdgcn_rcpf(1.0f + __builtin_amdgcn_exp2f(-1.44269504089f * v));
}
__device__ __forceinline__ float ftanh(float v) {
    float e = __builtin_amdgcn_exp2f(2.88539008178f * v);
    return 1.0f - 2.0f * __builtin_amdgcn_rcpf(e + 1.0f);
}
__device__ __forceinline__ float dot2f(u32 a, u32 w, float c) {
#if __has_builtin(__builtin_amdgcn_fdot2)
    return __builtin_amdgcn_fdot2(__builtin_bit_cast(h2, a), __builtin_bit_cast(h2, w), c, false);
#else
    h2 av = __builtin_bit_cast(h2, a), wv = __builtin_bit_cast(h2, w);
    return c + (float)av[0] * (float)wv[0] + (float)av[1] * (float)wv[1];
#endif
}
__device__ __forceinline__ u32 packw(float a, float b) {
    h2 v; v[0] = (f16)a; v[1] = (f16)b;
    return __builtin_bit_cast(u32, v);
}
// DPP adds: xor quad_perm (0xB1,0x4E) direction-free; row_ror 0x124/0x128 full-row
// rotate-accumulate (every lane ends with its row total, direction irrelevant).
template<int CTRL>
__device__ __forceinline__ float dpp_add(float x) {
    int y = __builtin_amdgcn_mov_dpp(__builtin_bit_cast(int, x), CTRL, 0xF, 0xF, true);
    return x + __builtin_bit_cast(float, y);
}
// masked DPP add for row_bcast steps: masked-off rows add 0 (update_dpp old=0).
template<int CTRL, int RMASK>
__device__ __forceinline__ float dpp_add_m(float x) {
    int y = __builtin_amdgcn_update_dpp(0, __builtin_bit_cast(int, x), CTRL, RMASK, 0xF, false);
    return x + __builtin_bit_cast(float, y);
}

// raw barrier: flush LDS ops, do NOT drain vmcnt (x prefetch + global stores stay in flight)
#define SYNCB() asm volatile("s_waitcnt lgkmcnt(0)\n\ts_barrier" ::: "memory")

#define ACCI(AV, W, IDX) do { u32 _a = (AV); \
    rr = dot2f(_a, W[0][IDX], rr); zz = dot2f(_a, W[1][IDX], zz); an = dot2f(_a, W[2][IDX], an); } while (0)
#define ACCH(AV, W, IDX) do { u32 _a = (AV); \
    rr = dot2f(_a, W[0][IDX], rr); zz = dot2f(_a, W[1][IDX], zz); hn = dot2f(_a, W[2][IDX], hn); } while (0)
#define ACCI4(U4, W, M0) do { uint4 _u4 = (U4); \
    ACCI(_u4.x, W, (M0)+0); ACCI(_u4.y, W, (M0)+1); ACCI(_u4.z, W, (M0)+2); ACCI(_u4.w, W, (M0)+3); } while (0)
#define ACCH4(U4, W, M0) do { uint4 _u4 = (U4); \
    ACCH(_u4.x, W, (M0)+0); ACCH(_u4.y, W, (M0)+1); ACCH(_u4.z, W, (M0)+2); ACCH(_u4.w, W, (M0)+3); } while (0)
#define RED4_Q() do { \
    rr = dpp_add<0xB1>(rr); rr = dpp_add<0x4E>(rr); \
    zz = dpp_add<0xB1>(zz); zz = dpp_add<0x4E>(zz); \
    an = dpp_add<0xB1>(an); an = dpp_add<0x4E>(an); \
    hn = dpp_add<0xB1>(hn); hn = dpp_add<0x4E>(hn); } while (0)
#define RED4_1() do { \
    rr = dpp_add<0xB1>(rr); zz = dpp_add<0xB1>(zz); \
    an = dpp_add<0xB1>(an); hn = dpp_add<0xB1>(hn); } while (0)

template<int N> struct IC { static constexpr int val = N; };

__global__ __launch_bounds__(NTH, 1) void rnnoise_kernel(
    const float* __restrict__ gx,
    const float* __restrict__ in_w,      const float* __restrict__ in_b,
    const float* __restrict__ vad_wih,   const float* __restrict__ vad_whh,
    const float* __restrict__ vad_bih,   const float* __restrict__ vad_bhh,
    const float* __restrict__ vad_out_w, const float* __restrict__ vad_out_b,
    const float* __restrict__ noise_wih, const float* __restrict__ noise_whh,
    const float* __restrict__ noise_bih, const float* __restrict__ noise_bhh,
    const float* __restrict__ den_wih,   const float* __restrict__ den_whh,
    const float* __restrict__ den_bih,   const float* __restrict__ den_bhh,
    const float* __restrict__ out_w,     const float* __restrict__ out_b,
    float* __restrict__ gains, float* __restrict__ vout)
{
    __shared__ __align__(16) f16 act[8][ACTW];   // 6 KB

    const int tid = threadIdx.x, wid = tid >> 6, lane = tid & 63;
    const int b = blockIdx.x;

    // zero all slots (initial states AND pads)
    #pragma unroll
    for (int i = 0; i < 3; ++i) {
        int idx = tid + i * NTH;
        if (idx < 8 * ACTW / 2) ((u32*)act)[idx] = 0u;
    }
    __syncthreads();

    // SIMD-balanced role map (wid%4 round-robin assumption):
    // SIMD0 {0:den, 4:noise, 8:vad}  SIMD1 {1:den, 5:noise, 9:noise}
    // SIMD2 {2:den, 6:den+out(0..10)} SIMD3 {3:den, 7:den+out(11..21)}
    const int role = (wid == 8) ? 2 : ((wid == 4 || wid == 5 || wid == 9) ? 1 : 0);

    if (role == 0) {
        // ========== DEN waves: t = k-5; wid6/7 also OUT: t = k-6 ==========
        const int dwi = (wid < 4) ? wid : (wid - 2);       // 0..5
        const int u = 16 * dwi + (lane >> 2), q = lane & 3;
        const bool ow = (wid == 6 || wid == 7);
        const int o = ((wid == 7) ? 11 : 0) + (lane >> 2); // output band (ow only)
        const int oc = (ow && o < 22) ? o : 0;
        const bool ostore = (ow && (lane & 3) == 0 && o < 22);
        u32 wdi[3][16], wdh[3][12], wo[12];
        #pragma unroll
        for (int g = 0; g < 3; ++g) {
            const float* wi = den_wih + (g * HD + u) * 114;   // cols [vad|noi|x] == DIN order
            #pragma unroll
            for (int m = 0; m < 16; ++m) {
                int c = 32 * q + 2 * m;
                float a  = (c     < 114) ? wi[c]     : 0.f;
                float b2 = (c + 1 < 114) ? wi[c + 1] : 0.f;
                wdi[g][m] = packw(a, b2);
            }
            const float* wh = den_whh + (g * HD + u) * HD + 24 * q;
            #pragma unroll
            for (int m = 0; m < 12; ++m) wdh[g][m] = packw(wh[2*m], wh[2*m+1]);
        }
        #pragma unroll
        for (int m = 0; m < 12; ++m)
            wo[m] = ow ? packw(out_w[oc*HD + 24*q + 2*m], out_w[oc*HD + 24*q + 2*m + 1]) : 0u;
        const float bdr  = den_bih[u]        + den_bhh[u];
        const float bdz  = den_bih[HD + u]   + den_bhh[HD + u];
        const float bdni = den_bih[2*HD + u];
        const float bdnh = den_bhh[2*HD + u];
        const float bo   = ow ? out_b[oc] : 0.f;
        float hreg = 0.f;
        uint4 a0{}, a1{}, a2{}, a3{};   // input frags of step t, read one tick early

        auto step = [&](auto PC, auto GC, int k) {
            constexpr int P = decltype(PC)::val;
            constexpr bool G = decltype(GC)::val != 0;
            constexpr int SHH = (P + 2) & 7;   // denh(k-6): hh operand AND out operand
            constexpr int SWR = (P + 3) & 7;   // write denh(k-5)
            constexpr int SNX = (P + 4) & 7;   // inputs of t=k-4 (refill for next tick)
            // issue hh read first; hide its latency under register input dots
            const uint4* hp = (const uint4*)&act[SHH][DH + 24 * q];
            uint4 h0 = hp[0], h1 = hp[1], h2 = hp[2];
            float rr = 0, zz = 0, an = 0, hn = 0;
            ACCI4(a0, wdi, 0); ACCI4(a1, wdi, 4); ACCI4(a2, wdi, 8); ACCI4(a3, wdi, 12);
            // refill EARLY (a0..a3 just consumed) — latency covered by hh dots + gates
            {
                const uint4* ip = (const uint4*)&act[SNX][DIN + 32 * q];
                a0 = ip[0]; a1 = ip[1]; a2 = ip[2]; a3 = ip[3];
            }
            ACCH4(h0, wdh, 0); ACCH4(h1, wdh, 4); ACCH4(h2, wdh, 8);
            RED4_Q();
            if (!G || (k >= 5 && k < TTT + 5)) {   // gates unmasked: sums replicated in quad
                float r = fsigm(rr + bdr);
                float z = fsigm(zz + bdz);
                float n = ftanh(an + bdni + r * (hn + bdnh));
                hreg = z * (hreg - n) + n;
                if (q == 0) act[SWR][DH + u] = (f16)hreg;
            }
            // OUT: gains(t=k-6) over denh(k-6) — operand IS h0..h2, no extra LDS
            if (ow && (!G || (k >= 6 && k < TTT + 6))) {
                float acc = 0;
                acc = dot2f(h0.x, wo[0], acc);  acc = dot2f(h0.y, wo[1], acc);
                acc = dot2f(h0.z, wo[2], acc);  acc = dot2f(h0.w, wo[3], acc);
                acc = dot2f(h1.x, wo[4], acc);  acc = dot2f(h1.y, wo[5], acc);
                acc = dot2f(h1.z, wo[6], acc);  acc = dot2f(h1.w, wo[7], acc);
                acc = dot2f(h2.x, wo[8], acc);  acc = dot2f(h2.y, wo[9], acc);
                acc = dot2f(h2.z, wo[10], acc); acc = dot2f(h2.w, wo[11], acc);
                acc = dpp_add<0xB1>(acc); acc = dpp_add<0x4E>(acc);
                if (ostore)
                    gains[((size_t)b * TTT + (k - 6)) * 22 + o] = fsigm(acc + bo);
            }
            SYNCB();
        };
        auto block8 = [&](auto GC, int k0) {
            step(IC<0>{},GC,k0);   step(IC<1>{},GC,k0+1); step(IC<2>{},GC,k0+2); step(IC<3>{},GC,k0+3);
            step(IC<4>{},GC,k0+4); step(IC<5>{},GC,k0+5); step(IC<6>{},GC,k0+6); step(IC<7>{},GC,k0+7);
        };
        #pragma clang loop unroll(disable)
        for (int k0 = 0; k0 < 16; k0 += 8) block8(IC<1>{}, k0);
        #pragma clang loop unroll(disable)
        for (int k0 = 16; k0 < TTT - 16; k0 += 8) block8(IC<0>{}, k0);
        #pragma clang loop unroll(disable)
        for (int k0 = TTT - 16; k0 < TTT + 8; k0 += 8) block8(IC<1>{}, k0);

    } else if (role == 1) {
        // ========== NOISE waves (wid 4,5,9): t = k-3 ==========
        const int nwi = (wid == 4) ? 0 : ((wid == 5) ? 1 : 2);
        const int u = 16 * nwi + (lane >> 2), q = lane & 3;
        u32 wni[3][12], wnh[3][8];
        #pragma unroll
        for (int g = 0; g < 3; ++g) {
            const float* wi = noise_wih + (g * HN + u) * 90;   // cols [tmp|vad|x] == NIN order
            #pragma unroll
            for (int m = 0; m < 12; ++m) {
                int c = 24 * q + 2 * m;
                float a  = (c     < 90) ? wi[c]     : 0.f;
                float b2 = (c + 1 < 90) ? wi[c + 1] : 0.f;
                wni[g][m] = packw(a, b2);
            }
            const float* wh = noise_whh + (g * HN + u) * HN;
            #pragma unroll
            for (int m = 0; m < 8; ++m) {
                int c = 16 * q + 2 * m;                        // NH dim (pad -> 0 weight)
                float a  = (c     < 48) ? wh[c]     : 0.f;
                float b2 = (c + 1 < 48) ? wh[c + 1] : 0.f;
                wnh[g][m] = packw(a, b2);
            }
        }
        const float bnr  = noise_bih[u]        + noise_bhh[u];
        const float bnz  = noise_bih[HN + u]   + noise_bhh[HN + u];
        const float bnni = noise_bih[2*HN + u];
        const float bnnh = noise_bhh[2*HN + u];
        float hreg = 0.f;
        uint4 a0{}, a1{}, a2{};   // input frags, read one tick early

        auto step = [&](auto PC, auto GC, int k) {
            constexpr int P = decltype(PC)::val;
            constexpr bool G = decltype(GC)::val != 0;
            constexpr int SHH = (P + 4) & 7;   // noih(k-4)
            constexpr int SWR = (P + 5) & 7;   // write noih(k-3)
            constexpr int SNX = (P + 6) & 7;   // inputs of t=k-2 (refill for next tick)
            const uint4* hp = (const uint4*)&act[SHH][NH + 16 * q];
            uint4 h0 = hp[0], h1 = hp[1];
            float rr = 0, zz = 0, an = 0, hn = 0;
            ACCI4(a0, wni, 0); ACCI4(a1, wni, 4); ACCI4(a2, wni, 8);
            {   // refill EARLY
                const uint4* ip = (const uint4*)&act[SNX][NIN + 24 * q];
                a0 = ip[0]; a1 = ip[1]; a2 = ip[2];
            }
            ACCH4(h0, wnh, 0); ACCH4(h1, wnh, 4);
            RED4_Q();
            if (!G || (k >= 3 && k < TTT + 3)) {
                float r = fsigm(rr + bnr);
                float z = fsigm(zz + bnz);
                float n = ftanh(an + bnni + r * (hn + bnnh));
                hreg = z * (hreg - n) + n;
                if (q == 0) {
                    f16 hh = (f16)hreg;
                    act[SWR][NH + u]       = hh;   // noise hh source
                    act[SWR][DIN + 24 + u] = hh;   // den input copy
                }
            }
            SYNCB();
        };
        auto block8 = [&](auto GC, int k0) {
            step(IC<0>{},GC,k0);   step(IC<1>{},GC,k0+1); step(IC<2>{},GC,k0+2); step(IC<3>{},GC,k0+3);
            step(IC<4>{},GC,k0+4); step(IC<5>{},GC,k0+5); step(IC<6>{},GC,k0+6); step(IC<7>{},GC,k0+7);
        };
        #pragma clang loop unroll(disable)
        for (int k0 = 0; k0 < 16; k0 += 8) block8(IC<1>{}, k0);
        #pragma clang loop unroll(disable)
        for (int k0 = 16; k0 < TTT - 16; k0 += 8) block8(IC<0>{}, k0);
        #pragma clang loop unroll(disable)
        for (int k0 = TTT - 16; k0 < TTT + 8; k0 += 8) block8(IC<1>{}, k0);

    } else {
        // ========== VAD wave (wid 8): x(k+1) stage + tmp(k) + vad GRU(t=k-1) + vad_out(t=k-1) ==========
        const int l = lane;
        const int u = (l < 48) ? (l >> 1) : 0, q2 = l & 1;
        u32 wvi[3][6], wvh[3][6], wtm[12];
        float bvr = 0, bvz = 0, bvni = 0, bvnh = 0, btm = 0, wvo_u = 0;
        if (l < 48) {
            #pragma unroll
            for (int g = 0; g < 3; ++g) {
                const float* wi = vad_wih + (g * HV + u) * HV + 12 * q2;
                const float* wh = vad_whh + (g * HV + u) * HV + 12 * q2;
                #pragma unroll
                for (int j = 0; j < 6; ++j) {
                    wvi[g][j] = packw(wi[2*j], wi[2*j+1]);
                    wvh[g][j] = packw(wh[2*j], wh[2*j+1]);
                }
            }
            #pragma unroll
            for (int j = 0; j < 12; ++j) {
                int c0 = 24 * q2 + 2 * j;
                float a = (c0     < INW) ? in_w[u * INW + c0]     : 0.f;
                float c = (c0 + 1 < INW) ? in_w[u * INW + c0 + 1] : 0.f;
                wtm[j] = packw(a, c);
            }
            bvr  = vad_bih[u]        + vad_bhh[u];
            bvz  = vad_bih[HV + u]   + vad_bhh[HV + u];
            bvni = vad_bih[2*HV + u];
            bvnh = vad_bhh[2*HV + u];
            btm  = in_b[u];
            if (q2 == 0) wvo_u = vad_out_w[u];
        }
        const float bvo = vad_out_b[0];
        float hreg = 0.f;

        // prologue: reg r = t&3 holds x(t) at staging time.
        // stage x(0) NOW (after init sync); regs hold x(1..4).
        float xa = 0, xb = 0, xc = 0, xd = 0;
        if (l < INW) {
            float x0v = gx[((size_t)b * TTT + 0) * INW + l];
            xb = gx[((size_t)b * TTT + 1) * INW + l];
            xc = gx[((size_t)b * TTT + 2) * INW + l];
            xd = gx[((size_t)b * TTT + 3) * INW + l];
            xa = gx[((size_t)b * TTT + 4) * INW + l];
            f16 xh = (f16)x0v;
            act[0][NIN + 48 + l] = xh;
            act[0][DIN + 72 + l] = xh;
        }

        auto step = [&](auto PC, auto GC, int k) {
            constexpr int P = decltype(PC)::val;
            constexpr bool G = decltype(GC)::val != 0;
            constexpr int SX = (P + 1) & 7;   // stage x(k+1) one tick early
            constexpr int ST = (P + 7) & 7;   // slot of t=k-1 (tmp read, vadh write)
            constexpr int SH = (P + 6) & 7;   // vadh(k-2)
            constexpr int XR = (P + 1) & 3;   // x phase register index for x(k+1)
            // issue ALL step-input LDS reads first (each >=1 barrier old) to cover latency
            const uint2* tp = (const uint2*)&act[ST][NIN + 12 * q2];       // tmp(k-1)
            uint2 t0 = tp[0], t1 = tp[1], t2 = tp[2];
            const uint2* hp = (const uint2*)&act[SH][NIN + 24 + 12 * q2];  // vadh(k-2)
            uint2 g0 = hp[0], g1 = hp[1], g2 = hp[2];
            const uint4* xp = (const uint4*)&act[P][NIN + 48 + 24 * q2];   // x(k)
            uint4 xv0 = xp[0], xv1 = xp[1], xv2 = xp[2];
            if ((!G || k + 1 < TTT) && l < INW) {   // stage x(k+1) into slot SX
                float xv;
                if constexpr (XR == 0) xv = xa; else if constexpr (XR == 1) xv = xb;
                else if constexpr (XR == 2) xv = xc; else xv = xd;
                f16 xh = (f16)xv;
                act[SX][NIN + 48 + l] = xh;
                act[SX][DIN + 72 + l] = xh;
            }
            if ((!G || k + 5 < TTT) && l < INW) {   // refill phase register with x(k+5)
                float xv = gx[((size_t)b * TTT + (k + 5)) * INW + l];
                if constexpr (XR == 0) xa = xv; else if constexpr (XR == 1) xb = xv;
                else if constexpr (XR == 2) xc = xv; else xd = xv;
            }
            if (!G || (k >= 1 && k <= TTT)) {       // vad GRU t = k-1
                float rr = 0, zz = 0, an = 0, hn = 0;
                ACCI(t0.x, wvi, 0); ACCI(t0.y, wvi, 1);
                ACCH(g0.x, wvh, 0); ACCH(g0.y, wvh, 1);
                ACCI(t1.x, wvi, 2); ACCI(t1.y, wvi, 3);
                ACCH(g1.x, wvh, 2); ACCH(g1.y, wvh, 3);
                ACCI(t2.x, wvi, 4); ACCI(t2.y, wvi, 5);
                ACCH(g2.x, wvh, 4); ACCH(g2.y, wvh, 5);
                RED4_1();
                // gates unmasked (pair-sums replicated in both team lanes)
                float r = fsigm(rr + bvr);
                float z = fsigm(zz + bvz);
                float n = ftanh(an + bvni + r * (hn + bvnh));
                hreg = z * (hreg - n) + n;
                if (l < 48 && q2 == 0) {
                    f16 hh = (f16)hreg;
                    act[ST][NIN + 24 + u] = hh;   // noise/vad hh source
                    act[ST][DIN + u]      = hh;   // den input copy
                }
                // vad_out(t): all-DPP full-wave reduce; total lands in lane 63.
                float val = (l < 48 && q2 == 0) ? (wvo_u * hreg) : 0.f;
                val = dpp_add<0xB1>(val);  val = dpp_add<0x4E>(val);
                val = dpp_add<0x124>(val); val = dpp_add<0x128>(val);     // row totals
                val = dpp_add_m<0x142, 0xA>(val);   // rows 1,3 += prev row's lane15/47
                val = dpp_add_m<0x143, 0xC>(val);   // rows 2,3 += lane31 (T0+T1)
                if (l == 63) vout[(size_t)b * TTT + (k - 1)] = fsigm(val + bvo);
            }
            if (!G || k < TTT) {    // tmp(k) from x(k) staged LAST tick (xv0..2 preloaded)
                float acc = 0;
                acc = dot2f(xv0.x, wtm[0], acc);  acc = dot2f(xv0.y, wtm[1], acc);
                acc = dot2f(xv0.z, wtm[2], acc);  acc = dot2f(xv0.w, wtm[3], acc);
                acc = dot2f(xv1.x, wtm[4], acc);  acc = dot2f(xv1.y, wtm[5], acc);
                acc = dot2f(xv1.z, wtm[6], acc);  acc = dot2f(xv1.w, wtm[7], acc);
                acc = dot2f(xv2.x, wtm[8], acc);  acc = dot2f(xv2.y, wtm[9], acc);
                acc = dot2f(xv2.z, wtm[10], acc); acc = dot2f(xv2.w, wtm[11], acc);
                acc = dpp_add<0xB1>(acc);
                if (l < 48 && q2 == 0) act[P][NIN + u] = (f16)ftanh(acc + btm);
            }
            SYNCB();
        };
        auto block8 = [&](auto GC, int k0) {
            step(IC<0>{},GC,k0);   step(IC<1>{},GC,k0+1); step(IC<2>{},GC,k0+2); step(IC<3>{},GC,k0+3);
            step(IC<4>{},GC,k0+4); step(IC<5>{},GC,k0+5); step(IC<6>{},GC,k0+6); step(IC<7>{},GC,k0+7);
        };
        #pragma clang loop unroll(disable)
        for (int k0 = 0; k0 < 16; k0 += 8) block8(IC<1>{}, k0);
        #pragma clang loop unroll(disable)
        for (int k0 = 16; k0 < TTT - 16; k0 += 8) block8(IC<0>{}, k0);
        #pragma clang loop unroll(disable)
        for (int k0 = TTT - 16; k0 < TTT + 8; k0 += 8) block8(IC<1>{}, k0);
    }
}

extern "C" void kernel_launch(void* const* d_in, const int* in_sizes, int n_in,
                              void* d_out, int out_size, void* d_ws, size_t ws_size,
                              hipStream_t stream) {
    (void)in_sizes; (void)n_in; (void)d_ws; (void)ws_size; (void)out_size;
    const float* gx        = (const float*)d_in[0];
    const float* in_w      = (const float*)d_in[1];
    const float* in_b      = (const float*)d_in[2];
    const float* vad_wih   = (const float*)d_in[3];
    const float* vad_whh   = (const float*)d_in[4];
    const float* vad_bih   = (const float*)d_in[5];
    const float* vad_bhh   = (const float*)d_in[6];
    const float* vad_out_w = (const float*)d_in[7];
    const float* vad_out_b = (const float*)d_in[8];
    const float* noise_wih = (const float*)d_in[9];
    const float* noise_whh = (const float*)d_in[10];
    const float* noise_bih = (const float*)d_in[11];
    const float* noise_bhh = (const float*)d_in[12];
    const float* den_wih   = (const float*)d_in[13];
    const float* den_whh   = (const float*)d_in[14];
    const float* den_bih   = (const float*)d_in[15];
    const float* den_bhh   = (const float*)d_in[16];
    const float* out_w     = (const float*)d_in[17];
    const float* out_b     = (const float*)d_in[18];
    float* gains = (float*)d_out;
    float* vout  = (float*)d_out + (size_t)TB * (size_t)TTT * 22;

    rnnoise_kernel<<<dim3(TB), dim3(NTH), 0, stream>>>(
        gx, in_w, in_b, vad_wih, vad_whh, vad_bih, vad_bhh, vad_out_w, vad_out_b,
        noise_wih, noise_whh, noise_bih, noise_bhh, den_wih, den_whh, den_bih, den_bhh,
        out_w, out_b, gains, vout);
}